// Round 13
// baseline (388.645 us; speedup 1.0000x reference)
//
#include <hip/hip_runtime.h>
#include <hip/hip_fp16.h>
#include <cstdint>

#define NN 100000
#define NE 1600000
#define INDIM 165
#define HID 64

// dst-bucket partition: bucket = dst >> BSH, BNODES nodes per bucket
constexpr int BSH = 7;
constexpr int BNODES = 128;               // 1 << BSH
constexpr int NBUK = (NN + BNODES - 1) / BNODES; // 782
constexpr int SC_CHUNK = 8192;            // edges per scatter block

// ---------------- bucket histogram ----------------

__global__ __launch_bounds__(256) void k_bhist(const int* __restrict__ dst,
                                               int* __restrict__ bhist, int ne) {
    __shared__ int h[NBUK];
    for (int b = threadIdx.x; b < NBUK; b += 256) h[b] = 0;
    __syncthreads();
    for (int e = blockIdx.x * blockDim.x + threadIdx.x; e < ne;
         e += gridDim.x * blockDim.x)
        atomicAdd(&h[dst[e] >> BSH], 1);
    __syncthreads();
    for (int b = threadIdx.x; b < NBUK; b += 256)
        if (h[b]) atomicAdd(&bhist[b], h[b]);
}

// ---------------- scan of 782 bucket counts (single block) ----------------

__global__ __launch_bounds__(256) void k_bscan(const int* __restrict__ bhist,
                                               int* __restrict__ bbase,
                                               int* __restrict__ bcursor) {
    __shared__ int wsum[4];
    const int tid = threadIdx.x, lane = tid & 63, wid = tid >> 6;
    int v[4];
    int tsum = 0;
#pragma unroll
    for (int i = 0; i < 4; ++i) {
        int idx = tid * 4 + i;
        v[i] = (idx < NBUK) ? bhist[idx] : 0;
        tsum += v[i];
    }
    int x = tsum;
#pragma unroll
    for (int off = 1; off < 64; off <<= 1) {
        int y = __shfl_up(x, off, 64);
        if (lane >= off) x += y;
    }
    if (lane == 63) wsum[wid] = x;
    __syncthreads();
    int woff = 0;
#pragma unroll
    for (int w = 0; w < 4; ++w)
        if (w < wid) woff += wsum[w];
    int run = woff + x - tsum;
#pragma unroll
    for (int i = 0; i < 4; ++i) {
        int idx = tid * 4 + i;
        if (idx < NBUK) { bbase[idx] = run; bcursor[idx] = run; }
        run += v[i];
    }
    if (tid == 255) bbase[NBUK] = woff + x; // grand total (= ne)
}

// ---------------- partition edges into bucket-major (src,dst) pairs --------

__global__ __launch_bounds__(256) void k_scatter(const int* __restrict__ src,
                                                 const int* __restrict__ dst,
                                                 int* __restrict__ bcursor,
                                                 int2* __restrict__ E2, int ne) {
    __shared__ int hist[NBUK];
    __shared__ int base[NBUK];
    const int tid = threadIdx.x;
    const int cs = blockIdx.x * SC_CHUNK;
    for (int b = tid; b < NBUK; b += 256) hist[b] = 0;
    __syncthreads();
    unsigned pack[SC_CHUNK / 256];
#pragma unroll 8
    for (int i = 0; i < SC_CHUNK / 256; ++i) {
        int e = cs + i * 256 + tid;
        if (e < ne) {
            int b = dst[e] >> BSH;
            int r = atomicAdd(&hist[b], 1);      // rank within (block,bucket)
            pack[i] = (unsigned)((b << 13) | r); // b<=781 (10b), r<8192 (13b)
        } else {
            pack[i] = 0xFFFFFFFFu;
        }
    }
    __syncthreads();
    for (int b = tid; b < NBUK; b += 256) {
        int c = hist[b];
        base[b] = c ? atomicAdd(&bcursor[b], c) : 0;
    }
    __syncthreads();
#pragma unroll 8
    for (int i = 0; i < SC_CHUNK / 256; ++i) {
        if (pack[i] != 0xFFFFFFFFu) {
            int e = cs + i * 256 + tid;
            int b = pack[i] >> 13, r = pack[i] & 8191;
            E2[base[b] + r] = make_int2(src[e], dst[e]);
        }
    }
}

// ---------------- per-bucket CSR build ----------------

__global__ __launch_bounds__(256) void k_csrb(const int2* __restrict__ E2,
                                              const int* __restrict__ bbase,
                                              int* __restrict__ rowptr,
                                              int* __restrict__ col, int n) {
    __shared__ int cnt[BNODES];
    __shared__ int pref[BNODES];
    const int tid = threadIdx.x;
    const int bs = bbase[blockIdx.x], be = bbase[blockIdx.x + 1];
    for (int i = tid; i < BNODES; i += 256) cnt[i] = 0;
    __syncthreads();
    for (int e = bs + tid; e < be; e += 256)
        atomicAdd(&cnt[E2[e].y & (BNODES - 1)], 1);
    __syncthreads();
    if (tid < 64) { // wave 0 scans 128 counts, 2/lane (wave-uniform branch)
        int c0 = cnt[tid * 2], c1 = cnt[tid * 2 + 1];
        int s = c0 + c1;
        int x = s;
#pragma unroll
        for (int off = 1; off < 64; off <<= 1) {
            int y = __shfl_up(x, off, 64);
            if (tid >= off) x += y;
        }
        int ex = x - s; // exclusive
        pref[tid * 2] = ex;
        pref[tid * 2 + 1] = ex + c0;
    }
    __syncthreads();
    const int nodeBase = blockIdx.x * BNODES;
    for (int i = tid; i < BNODES; i += 256) {
        int gn = nodeBase + i;
        if (gn < n) rowptr[gn] = bs + pref[i];
        cnt[i] = 0; // reuse as cursor
    }
    __syncthreads();
    for (int e = bs + tid; e < be; e += 256) {
        int2 pr = E2[e];
        int d = pr.y & (BNODES - 1);
        int r = atomicAdd(&cnt[d], 1);
        col[bs + pref[d] + r] = pr.x;
    }
    if (blockIdx.x == 0 && tid == 0) rowptr[n] = bbase[NBUK];
}

// ---------------- fused dual linear: Y(fp16) = X@Wl, R(fp32) = X@Wr -------
// r12 post-mortem: LDS pipe charges ~12 cyc PER ds_read_b128 INSTRUCTION
// (broadcast irrelevant — r11 vs r12 mapping swap changed nothing). Duty
// ceiling = (FMA-instr per b128)/24. 4x8 microtile: 32/3 = 10.7 -> 45%
// (measured 47-49%). Fix: 8x8 microtile -> 64 FMA / 4 b128 = 16 -> 67%
// ceiling. Keep the grid large: block = 128 threads (2 waves), MT=64,
// N=128 -> 1563 blocks, LDS 25 KB -> 6 blocks/CU = 12 waves/CU (37.5%).

template <int K>
__global__ __launch_bounds__(128) void k_linear(const float* __restrict__ X,
                                                const float* __restrict__ Wl,
                                                const float* __restrict__ Wr,
                                                __half* __restrict__ Y,
                                                float* __restrict__ R, int n) {
    constexpr int KC = 32;
    constexpr int MT = 64;
    constexpr int LDX = 68; // 16B-aligned rows; staging writes 4-way (rare)
    __shared__ float Xs[KC][LDX]; // Xs[k][m]
    __shared__ float Ws[KC][128]; // split lo/hi layout (r9): 2-way reads, free

    const int tid = threadIdx.x;
    const int m0 = (tid >> 4) * 8;  // 8 nodes per thread (8 m-groups)
    const int n0 = (tid & 15) * 8;  // 8 cols per thread (16 n-groups)
    const int nodeBase = blockIdx.x * MT;

    float acc[8][8];
#pragma unroll
    for (int i = 0; i < 8; ++i)
#pragma unroll
        for (int j = 0; j < 8; ++j) acc[i][j] = 0.f;

    for (int c = 0; c < K; c += KC) {
        const int kw = (K - c < KC) ? (K - c) : KC;
        __syncthreads();
        // stage X: e -> k = e&31 (consec lanes = consec k: coalesced), m = e>>5
#pragma unroll
        for (int i = 0; i < 16; ++i) {
            int e = tid + i * 128;
            int k = e & 31;
            int m = e >> 5;
            int gn = nodeBase + m;
            if (gn >= n) gn = n - 1;
            Xs[k][m] = (k < kw) ? X[(size_t)gn * K + c + k] : 0.f;
        }
        // stage W: logical float4 col nf -> split lo/hi position
#pragma unroll
        for (int i = 0; i < 8; ++i) {
            int v = tid + i * 128;
            int k = v >> 5;
            int nf = (v & 31) * 4;
            float4 w;
            if (k < kw) {
                const float* sp = (nf < 64) ? (Wl + (size_t)(c + k) * HID + nf)
                                            : (Wr + (size_t)(c + k) * HID + (nf - 64));
                w = *(const float4*)sp;
            } else {
                w = make_float4(0.f, 0.f, 0.f, 0.f);
            }
            const int pos = ((nf >> 2) & 1) * 64 + (nf >> 3) * 4;
            *(float4*)&Ws[k][pos] = w;
        }
        __syncthreads();
#pragma unroll 2
        for (int kk = 0; kk < KC; ++kk) {
            const float4 xa = *(const float4*)&Xs[kk][m0];
            const float4 xb = *(const float4*)&Xs[kk][m0 + 4];
            const float4 wa = *(const float4*)&Ws[kk][n0 >> 1];        // lo
            const float4 wb = *(const float4*)&Ws[kk][64 + (n0 >> 1)]; // hi
            const float xm[8] = {xa.x, xa.y, xa.z, xa.w, xb.x, xb.y, xb.z, xb.w};
            const float wn[8] = {wa.x, wa.y, wa.z, wa.w, wb.x, wb.y, wb.z, wb.w};
#pragma unroll
            for (int i = 0; i < 8; ++i)
#pragma unroll
                for (int j = 0; j < 8; ++j)
                    acc[i][j] = fmaf(xm[i], wn[j], acc[i][j]);
        }
    }

    // epilogue: n0<64 -> Y (fp16, one 16B packed store/row), else -> R (fp32)
    if (n0 < HID) {
#pragma unroll
        for (int i = 0; i < 8; ++i) {
            const int gn = nodeBase + m0 + i;
            if (gn < n) {
                union { __half2 h2[4]; uint4 u4; } u;
#pragma unroll
                for (int q = 0; q < 4; ++q)
                    u.h2[q] = __float22half2_rn(
                        make_float2(acc[i][2 * q], acc[i][2 * q + 1]));
                *(uint4*)&Y[(size_t)gn * HID + n0] = u.u4; // 16B aligned
            }
        }
    } else {
        const int nc = n0 - HID;
#pragma unroll
        for (int i = 0; i < 8; ++i) {
            const int gn = nodeBase + m0 + i;
            if (gn < n) {
                *(float4*)&R[(size_t)gn * HID + nc] =
                    make_float4(acc[i][0], acc[i][1], acc[i][2], acc[i][3]);
                *(float4*)&R[(size_t)gn * HID + nc + 4] =
                    make_float4(acc[i][4], acc[i][5], acc[i][6], acc[i][7]);
            }
        }
    }
}

// ---------------- aggregation (+ optional fused classifier) ----------------
// Wave per node; Y fp16, lane reads __half2 (half-wave = one 128B row).
// L3-latency-bound gather -> 8 loads (16 edges) in flight per iteration
// (avg deg 16 covered in one unrolled batch). Redistribute shuffles in
// uniform CF (EXEC-gated ds_bpermute, r5 bug).

template <bool CLS>
__global__ __launch_bounds__(256) void k_agg(const __half* __restrict__ Y,
                                             const float* __restrict__ Rm,
                                             const float* __restrict__ bias,
                                             const int* __restrict__ rowptr,
                                             const int* __restrict__ col,
                                             float* __restrict__ H,
                                             const float* __restrict__ Wc,
                                             const float* __restrict__ bc,
                                             float* __restrict__ out, int n) {
    const int lane = threadIdx.x & 63;
    const int node = blockIdx.x * 4 + (threadIdx.x >> 6);
    if (node >= n) return;
    const int half_ = lane >> 5;       // which edge of the pair
    const int fl = (lane & 31) * 2;    // feature pair
    const int s = rowptr[node], e = rowptr[node + 1];
    float ax = 0.f, ay = 0.f;
    int i = s + half_;
    for (; i + 14 < e; i += 16) {
        int sx[8];
#pragma unroll
        for (int q = 0; q < 8; ++q) sx[q] = col[i + 2 * q];
        float2 yv[8];
#pragma unroll
        for (int q = 0; q < 8; ++q)
            yv[q] = __half22float2(*(const __half2*)&Y[(size_t)sx[q] * HID + fl]);
#pragma unroll
        for (int q = 0; q < 8; ++q) { ax += yv[q].x; ay += yv[q].y; }
    }
    for (; i + 6 < e; i += 8) {
        int s0 = col[i], s1 = col[i + 2], s2 = col[i + 4], s3 = col[i + 6];
        float2 y0 = __half22float2(*(const __half2*)&Y[(size_t)s0 * HID + fl]);
        float2 y1 = __half22float2(*(const __half2*)&Y[(size_t)s1 * HID + fl]);
        float2 y2 = __half22float2(*(const __half2*)&Y[(size_t)s2 * HID + fl]);
        float2 y3 = __half22float2(*(const __half2*)&Y[(size_t)s3 * HID + fl]);
        ax += (y0.x + y1.x) + (y2.x + y3.x);
        ay += (y0.y + y1.y) + (y2.y + y3.y);
    }
    for (; i < e; i += 2) {
        float2 yv = __half22float2(*(const __half2*)&Y[(size_t)col[i] * HID + fl]);
        ax += yv.x;
        ay += yv.y;
    }
    ax += __shfl_xor(ax, 32, 64);
    ay += __shfl_xor(ay, 32, 64);
    const float vx = __shfl(ax, lane >> 1, 64);
    const float vy = __shfl(ay, lane >> 1, 64);
    const float acc = (lane & 1) ? vy : vx;
    const int deg = e - s;
    float h = acc / (float)(deg > 1 ? deg : 1) + bias[lane] + Rm[(size_t)node * HID + lane];
    h = fmaxf(h, 0.f);
    if (!CLS) {
        H[(size_t)node * HID + lane] = h;
    } else {
        float p0 = h * Wc[lane * 2 + 0];
        float p1 = h * Wc[lane * 2 + 1];
#pragma unroll
        for (int off = 32; off > 0; off >>= 1) {
            p0 += __shfl_xor(p0, off, 64);
            p1 += __shfl_xor(p1, off, 64);
        }
        if (lane == 0) {
            out[(size_t)node * 2 + 0] = p0 + bc[0];
            out[(size_t)node * 2 + 1] = p1 + bc[1];
        }
    }
}

// ---------------- launch ----------------

extern "C" void kernel_launch(void* const* d_in, const int* in_sizes, int n_in,
                              void* d_out, int out_size, void* d_ws, size_t ws_size,
                              hipStream_t stream) {
    const float* x   = (const float*)d_in[0];
    const int*   ei  = (const int*)d_in[1];
    const float* W1l = (const float*)d_in[2];
    const float* b1  = (const float*)d_in[3];
    const float* W1r = (const float*)d_in[4];
    const float* W2l = (const float*)d_in[5];
    const float* b2  = (const float*)d_in[6];
    const float* W2r = (const float*)d_in[7];
    const float* Wc  = (const float*)d_in[8];
    const float* bc  = (const float*)d_in[9];
    float* out = (float*)d_out;
    const int* src = ei;
    const int* dst = ei + NE;

    char* base = (char*)d_ws;
    size_t off = 0;
    auto alloc = [&](size_t bytes) {
        void* p = base + off;
        off = (off + bytes + 255) & ~(size_t)255;
        return p;
    };
    int*    bhist   = (int*)alloc((size_t)NBUK * 4);
    int*    bbase   = (int*)alloc((size_t)(NBUK + 1) * 4);
    int*    bcursor = (int*)alloc((size_t)NBUK * 4);
    int*    rowptr  = (int*)alloc((size_t)(NN + 1) * 4);
    int*    col     = (int*)alloc((size_t)NE * 4);
    // E2 (12.8 MB) is dead after k_csrb -> alias it under Y (fp16, 12.8 MB)
    __half* Y       = (__half*)alloc((size_t)NN * HID * 2 + 256);
    float*  R       = (float*)alloc((size_t)NN * HID * 4);
    float*  H1      = (float*)alloc((size_t)NN * HID * 4);
    int2*   E2      = (int2*)Y;

    const int sb = (NE + SC_CHUNK - 1) / SC_CHUNK; // 196

    hipMemsetAsync(bhist, 0, (size_t)NBUK * 4, stream);
    k_bhist<<<sb, 256, 0, stream>>>(dst, bhist, NE);
    k_bscan<<<1, 256, 0, stream>>>(bhist, bbase, bcursor);
    k_scatter<<<sb, 256, 0, stream>>>(src, dst, bcursor, E2, NE);
    k_csrb<<<NBUK, 256, 0, stream>>>(E2, bbase, rowptr, col, NN);

    k_linear<INDIM><<<(NN + 63) / 64, 128, 0, stream>>>(x, W1l, W1r, Y, R, NN);
    k_agg<false><<<(NN + 3) / 4, 256, 0, stream>>>(Y, R, b1, rowptr, col, H1,
                                                   nullptr, nullptr, nullptr, NN);
    k_linear<HID><<<(NN + 63) / 64, 128, 0, stream>>>(H1, W2l, W2r, Y, R, NN);
    k_agg<true><<<(NN + 3) / 4, 256, 0, stream>>>(Y, R, b2, rowptr, col, nullptr,
                                                  Wc, bc, out, NN);
}